// Round 3
// baseline (1189.231 us; speedup 1.0000x reference)
//
#include <hip/hip_runtime.h>
#include <math.h>

#define NT 16384
#define DIM 4096
#define NE 64
#define TOPK 8
#define TM 16
#define DB (DIM / 4) /* 1024 float4 chunks per row */

// d_out layout (floats), concatenated flat in reference return order:
#define OFF_IDS 0
#define OFF_PROBS (NT * TOPK)              /* 131072 */
#define OFF_SIDS (2 * NT * TOPK)           /* 262144 */
#define OFF_SPROBS (OFF_SIDS + NT * 2)     /* 294912 */
#define OFF_AUX (OFF_SPROBS + NT * 2)      /* 327680 */

// Pack W[64][4096] -> Wp[db][e][4] so lane e reads a contiguous float4 per db.
__global__ void pack_w_kernel(const float* __restrict__ W, float* __restrict__ Wp) {
    int idx = blockIdx.x * blockDim.x + threadIdx.x;  // 0..262143
    int j = idx & 3;
    int e = (idx >> 2) & 63;
    int db = idx >> 8;
    Wp[idx] = W[e * DIM + db * 4 + j];
}

__launch_bounds__(256, 1)
__global__ void router_main_kernel(const float* __restrict__ x,
                                   const float* __restrict__ Wp,
                                   const float* __restrict__ bias,
                                   float* __restrict__ out,
                                   float* __restrict__ partials) {
    const int lane = threadIdx.x & 63;
    const int wave = threadIdx.x >> 6;  // 0..3
    const int waveId = blockIdx.x * 4 + wave;  // 0..1023
    // Force SGPR so x loads become uniform s_load_dwordx4 (scalar path).
    const int tokBase = __builtin_amdgcn_readfirstlane(waveId * TM);

    const float4* __restrict__ x4 = (const float4*)x;
    const float4* __restrict__ w4 = (const float4*)Wp;

    // fp64 accumulation: logits exact to ~1e-13 so top-k ordering matches the
    // fp64 numpy reference (fp32 serial accumulation flipped near-tie ranks).
    double acc[TM];
#pragma unroll
    for (int t = 0; t < TM; ++t) acc[t] = 0.0;

#pragma unroll 2
    for (int db = 0; db < DB; ++db) {
        float4 wv = w4[db * 64 + lane];  // coalesced: 16B/lane, 1KB/wave
        const double wx = (double)wv.x, wy = (double)wv.y,
                     wz = (double)wv.z, ww = (double)wv.w;
#pragma unroll
        for (int t = 0; t < TM; ++t) {
            float4 xv = x4[(tokBase + t) * DB + db];  // wave-uniform -> s_load
            acc[t] = fma((double)xv.x, wx, acc[t]);
            acc[t] = fma((double)xv.y, wy, acc[t]);
            acc[t] = fma((double)xv.z, wz, acc[t]);
            acc[t] = fma((double)xv.w, ww, acc[t]);
        }
    }

    const double b = (double)bias[lane];
    float pacc = 0.f;  // per-lane (= per-expert) prob accumulation over TM tokens

    for (int t = 0; t < TM; ++t) {
        const int tok = tokBase + t;
        const double lvd = acc[t] + b;  // fp64 logit for (tok, expert=lane)
        const float lv = (float)lvd;

        // softmax over the 64 lanes (fp32 is fine: 2% rel threshold on probs)
        float m = lv;
#pragma unroll
        for (int off = 32; off; off >>= 1) m = fmaxf(m, __shfl_xor(m, off, 64));
        const float ev = __expf(lv - m);
        float s = ev;
#pragma unroll
        for (int off = 32; off; off >>= 1) s += __shfl_xor(s, off, 64);
        const float prob = ev / s;
        pacc += prob;

        // top-8 by fp64 logit (monotone with prob); tie-break: lower index
        double cur = lvd;
        float myid = 0.f, mypv = 0.f;
        for (int k = 0; k < TOPK; ++k) {
            double bv = cur;
            int bi = lane;
#pragma unroll
            for (int off = 32; off; off >>= 1) {
                double ov = __shfl_xor(bv, off, 64);
                int oi = __shfl_xor(bi, off, 64);
                if (ov > bv || (ov == bv && oi < bi)) { bv = ov; bi = oi; }
            }
            const float bp = __shfl(prob, bi, 64);
            if (lane == k) { myid = (float)bi; mypv = bp; }
            if (lane == bi) cur = -INFINITY;
        }
        if (lane < TOPK) {
            out[OFF_IDS + tok * TOPK + lane] = myid;
            out[OFF_PROBS + tok * TOPK + lane] = mypv;
        }
        if (lane < 2) {
            out[OFF_SIDS + tok * 2 + lane] = (float)lane;
            out[OFF_SPROBS + tok * 2 + lane] = 0.5f;
        }
    }

    partials[waveId * 64 + lane] = pacc;  // deterministic (no atomics)
}

__global__ void reduce_aux_kernel(const float* __restrict__ partials,
                                  float* __restrict__ out) {
    __shared__ float sm[256];
    const int t = threadIdx.x;
    const int e = t & 63;
    const int g = t >> 6;
    float s = 0.f;
    for (int i = g; i < 1024; i += 4) s += partials[i * 64 + e];
    sm[t] = s;
    __syncthreads();
    if (t < 64) {
        float tot = sm[t] + sm[t + 64] + sm[t + 128] + sm[t + 192];
        float mean = tot * (1.0f / (float)NT);
        float sq = mean * mean;
#pragma unroll
        for (int off = 32; off; off >>= 1) sq += __shfl_xor(sq, off, 64);
        if (t == 0) out[OFF_AUX] = 0.01f * (sq * (1.0f / (float)NE));
    }
}

extern "C" void kernel_launch(void* const* d_in, const int* in_sizes, int n_in,
                              void* d_out, int out_size, void* d_ws, size_t ws_size,
                              hipStream_t stream) {
    const float* x = (const float*)d_in[0];
    const float* W = (const float*)d_in[1];
    const float* bias = (const float*)d_in[2];
    float* out = (float*)d_out;

    float* Wp = (float*)d_ws;                    // 262144 floats = 1 MB
    float* partials = (float*)d_ws + 262144;     // 65536 floats = 256 KB

    pack_w_kernel<<<1024, 256, 0, stream>>>(W, Wp);
    router_main_kernel<<<256, 256, 0, stream>>>(x, Wp, bias, out, partials);
    reduce_aux_kernel<<<1, 256, 0, stream>>>(partials, out);
}